// Round 3
// baseline (323.296 us; speedup 1.0000x reference)
//
#include <hip/hip_runtime.h>
#include <hip/hip_bf16.h>

#define NEG 0.01f
#define EPS 1e-5f

typedef __attribute__((ext_vector_type(8))) short short8;
typedef __attribute__((ext_vector_type(4))) float floatx4;

__device__ inline unsigned short f2bf(float f) {
    __hip_bfloat16 h = __float2bfloat16(f);
    union { __hip_bfloat16 h; unsigned short u; } cv; cv.h = h;
    return cv.u;
}

// ------------------------------- head: render + weight transform (fused) ----
// blocks [0,1024): render batch b=blk>>4, 256-px chunk blk&15
// blocks [1024,5144): weight transform, 1,054,720 threads total
__global__ __launch_bounds__(256) void head_kernel(const float* __restrict__ in,
                                                   unsigned short* __restrict__ out,
                                                   const float* __restrict__ w1,
                                                   const float* __restrict__ w2,
                                                   const float* __restrict__ w3,
                                                   unsigned short* __restrict__ wT1,
                                                   unsigned short* __restrict__ wT2,
                                                   unsigned short* __restrict__ wT3) {
    __shared__ float r0[46], r1[46], r2[46], r3[46];
    __shared__ float cls_s[46 * 14];
    if (blockIdx.x >= 1024) {
        int idx = (blockIdx.x - 1024) * 256 + threadIdx.x;
        const float* w; unsigned short* wT; int CIN, CPLOG, SUB, COLOG;
        if (idx < 30720) { w = w1; wT = wT1; CIN = 14; CPLOG = 4; SUB = 3; COLOG = 6; }
        else if (idx < 235520) { idx -= 30720; w = w2; wT = wT2; CIN = 64; CPLOG = 6; SUB = 10; COLOG = 7; }
        else if (idx < 1054720) { idx -= 235520; w = w3; wT = wT3; CIN = 128; CPLOG = 7; SUB = 20; COLOG = 8; }
        else return;
        int kk = idx & 31;
        int co = (idx >> 5) & ((1 << COLOG) - 1);
        int s = idx >> (5 + COLOG);
        int kh = s / SUB, sub = s - kh * SUB;
        int kidx = sub * 32 + kk;
        int kw = kidx >> CPLOG;
        int ci = kidx & ((1 << CPLOG) - 1);
        float v = (kw < 5 && ci < CIN) ? w[((size_t)(co * CIN + ci) * 5 + kh) * 5 + kw] : 0.f;
        wT[idx] = f2bf(v);
        return;
    }
    int b = blockIdx.x >> 4;
    int chunk = blockIdx.x & 15;
    int tid = threadIdx.x;
    if (tid < 46) {
        const float* p = in + ((size_t)b * 46 + tid) * 18 + 14;
        float x = p[0] * 64.f, y = p[1] * 64.f, w = p[2] * 64.f, h = p[3] * 64.f;
        r0[tid] = x - 0.5f * w; r1[tid] = x + 0.5f * w;
        r2[tid] = y - 0.5f * h; r3[tid] = y + 0.5f * h;
    }
    for (int idx = tid; idx < 46 * 14; idx += 256) {
        int n = idx / 14, c = idx % 14;
        cls_s[idx] = in[((size_t)b * 46 + n) * 18 + c];
    }
    __syncthreads();
    // border zeroing: 528 border px, 33 per block
    if (tid < 33) {
        int j = chunk * 33 + tid;
        if (j < 528) {
            int y, x;
            if (j < 136) { y = j / 68; x = j - y * 68; }
            else if (j < 272) { int t = j - 136; int yy = t / 68; y = 66 + yy; x = t - yy * 68; }
            else { int t = j - 272; y = 2 + (t >> 2); int k = t & 3; x = (k < 2) ? k : 64 + k; }
            size_t zb = (((size_t)b * 68 + y) * 68 + x) * 16;
            short8 z;
#pragma unroll
            for (int i = 0; i < 8; ++i) z[i] = 0;
            *(short8*)(out + zb) = z;
            *(short8*)(out + zb + 8) = z;
        }
    }
    int pix = chunk * 256 + tid;
    float cx = (float)(pix & 63);
    float cy = (float)(pix >> 6);
    float acc[14];
#pragma unroll
    for (int c = 0; c < 14; ++c) acc[c] = 0.f;
    for (int n = 0; n < 46; ++n) {
        float x0 = r0[n], x1 = r1[n], y0 = r2[n], y1 = r3[n];
        float by = fminf(fmaxf(cy - y0, 0.f), 1.f) * fminf(fmaxf(y1 - cy, 0.f), 1.f);
        float bx = fminf(fmaxf(cx - x0, 0.f), 1.f) * fminf(fmaxf(x1 - cx, 0.f), 1.f);
        float kx0 = fmaxf(1.f - fabsf(cx - x0), 0.f);
        float kx1 = fmaxf(1.f - fabsf(cx - x1), 0.f);
        float ky0 = fmaxf(1.f - fabsf(cy - y0), 0.f);
        float ky1 = fmaxf(1.f - fabsf(cy - y1), 0.f);
        float r = fmaxf(fmaxf(kx0 * by, kx1 * by), fmaxf(ky0 * bx, ky1 * bx));
        if (r > 0.f) {
#pragma unroll
            for (int c = 0; c < 14; ++c) acc[c] = fmaf(cls_s[n * 14 + c], r, acc[c]);
        }
    }
    size_t obase = (((size_t)b * 68 + ((pix >> 6) + 2)) * 68 + ((pix & 63) + 2)) * 16;
    short8 v0, v1;
#pragma unroll
    for (int i = 0; i < 8; ++i) v0[i] = (short)f2bf(acc[i]);
#pragma unroll
    for (int i = 0; i < 6; ++i) v1[i] = (short)f2bf(acc[8 + i]);
    v1[6] = 0; v1[7] = 0;
    *(short8*)(out + obase) = v0;
    *(short8*)(out + obase + 8) = v1;
}

// ---------------------------------------- direct-operand MFMA conv ----------
// No LDS, no barriers in the main loop: B (transformed weights) is tiny and
// L2-resident, so each wave loads BOTH A (padded NHWC) and B fragments
// directly from global, double-buffered in registers. 512 blocks x 256 thr =
// 2 blocks/CU = 8 waves/CU = 2 waves/SIMD; waves are fully independent.
// KSEG>1: split-K with f32 atomicAdd epilogue (stats done by stats_part).
// KSEG==1: fused BN stats (shfl + LDS reduce + 1 atomic per channel/block).
template <int CP, int COUT, int HP, int LOG_OHW, int LOG_OW, int SUB,
          int NCO, int NT, int KSEG>
__global__ __launch_bounds__(256, 2) void conv_direct(
        const unsigned short* __restrict__ inP,
        const unsigned short* __restrict__ wT,
        float* __restrict__ outX,
        float* __restrict__ stacc) {
    constexpr int NSTEP_TOT = 5 * SUB;
    constexpr int NSTEP = NSTEP_TOT / KSEG;
    constexpr int COT = NT * 16;
    static_assert(NSTEP_TOT % KSEG == 0, "KSEG must divide steps");
    __shared__ float sred[4][2][COT];
    int tid = threadIdx.x;
    int wave = tid >> 6, lane = tid & 63, q = lane >> 4, l16 = lane & 15;
    // XCD-aware bijective swizzle (grid % 8 == 0): contiguous bm per XCD so
    // the NCO*KSEG blocks sharing an A-tile hit the same private L2.
    int cpx = gridDim.x >> 3;
    int lb = (blockIdx.x & 7) * cpx + (blockIdx.x >> 3);
    int bm = lb / (NCO * KSEG);
    int rem = lb - bm * (NCO * KSEG);
    int bco = rem / KSEG;
    int kseg = rem - bco * KSEG;
    int kbase = kseg * NSTEP;

    const short* aB[4];
#pragma unroll
    for (int f = 0; f < 4; ++f) {
        int m = bm * 256 + wave * 64 + f * 16 + l16;
        int b = m >> LOG_OHW;
        int ohw = m & ((1 << LOG_OHW) - 1);
        int oh = ohw >> LOG_OW, ow = ohw & ((1 << LOG_OW) - 1);
        aB[f] = (const short*)inP + ((size_t)((b * HP + 2 * oh) * HP + 2 * ow)) * CP + q * 8;
    }
    const short* bB[NT];
#pragma unroll
    for (int nt = 0; nt < NT; ++nt)
        bB[nt] = (const short*)wT + (size_t)bco * COT * 32 + ((nt * 16 + l16) * 4 + q) * 8;

    floatx4 acc[4][NT];
#pragma unroll
    for (int f = 0; f < 4; ++f)
#pragma unroll
        for (int nt = 0; nt < NT; ++nt) acc[f][nt] = (floatx4){0.f, 0.f, 0.f, 0.f};

    short8 afc[4], bfc[NT], afn[4], bfn[NT];
    {
        int gs = kbase;
        int kh = gs / SUB, sub = gs - kh * SUB;
#pragma unroll
        for (int f = 0; f < 4; ++f)
            afc[f] = *(const short8*)(aB[f] + (size_t)kh * HP * CP + sub * 32);
#pragma unroll
        for (int nt = 0; nt < NT; ++nt)
            bfc[nt] = *(const short8*)(bB[nt] + (size_t)gs * COUT * 32);
    }
#pragma unroll
    for (int s = 0; s < NSTEP; ++s) {
        if (s + 1 < NSTEP) {
            int gs = kbase + s + 1;
            int kh = gs / SUB, sub = gs - kh * SUB;
#pragma unroll
            for (int f = 0; f < 4; ++f)
                afn[f] = *(const short8*)(aB[f] + (size_t)kh * HP * CP + sub * 32);
#pragma unroll
            for (int nt = 0; nt < NT; ++nt)
                bfn[nt] = *(const short8*)(bB[nt] + (size_t)gs * COUT * 32);
        }
#pragma unroll
        for (int nt = 0; nt < NT; ++nt)
#pragma unroll
            for (int f = 0; f < 4; ++f)
                acc[f][nt] = __builtin_amdgcn_mfma_f32_16x16x32_bf16(afc[f], bfc[nt], acc[f][nt], 0, 0, 0);
        if (s + 1 < NSTEP) {
#pragma unroll
            for (int f = 0; f < 4; ++f) afc[f] = afn[f];
#pragma unroll
            for (int nt = 0; nt < NT; ++nt) bfc[nt] = bfn[nt];
        }
    }
    // epilogue
#pragma unroll
    for (int f = 0; f < 4; ++f)
#pragma unroll
        for (int nt = 0; nt < NT; ++nt)
#pragma unroll
            for (int rg = 0; rg < 4; ++rg) {
                int mg = bm * 256 + wave * 64 + f * 16 + q * 4 + rg;
                int co = bco * COT + nt * 16 + l16;
                if constexpr (KSEG > 1)
                    atomicAdd(&outX[(size_t)mg * COUT + co], acc[f][nt][rg]);
                else
                    outX[(size_t)mg * COUT + co] = acc[f][nt][rg];
            }
    if constexpr (KSEG == 1) {
        // fused BN stats
#pragma unroll
        for (int nt = 0; nt < NT; ++nt) {
            float s = 0.f, s2 = 0.f;
#pragma unroll
            for (int f = 0; f < 4; ++f)
#pragma unroll
                for (int rg = 0; rg < 4; ++rg) {
                    float v = acc[f][nt][rg];
                    s += v; s2 = fmaf(v, v, s2);
                }
            s += __shfl_xor(s, 16); s += __shfl_xor(s, 32);
            s2 += __shfl_xor(s2, 16); s2 += __shfl_xor(s2, 32);
            if (q == 0) {
                sred[wave][0][nt * 16 + l16] = s;
                sred[wave][1][nt * 16 + l16] = s2;
            }
        }
        __syncthreads();
        if (tid < COT) {
            float ts = 0.f, ts2 = 0.f;
#pragma unroll
            for (int w = 0; w < 4; ++w) { ts += sred[w][0][tid]; ts2 += sred[w][1][tid]; }
            atomicAdd(&stacc[bco * COT + tid], ts);
            atomicAdd(&stacc[COUT + bco * COT + tid], ts2);
        }
    }
}

// --------------------------------------------------- conv4 split-K GEMM -----
__global__ __launch_bounds__(256) void conv4_mfma(const unsigned short* __restrict__ A,
                                                  const float* __restrict__ w4,
                                                  float* __restrict__ h4) {
    constexpr int CH = 8, NCHUNK = 4;
    __shared__ short Bs[CH][64][40];
    int tid = threadIdx.x;
    int bco = blockIdx.x & 15;
    int ks = blockIdx.x >> 4;
    int wave = tid >> 6, lane = tid & 63, q = lane >> 4, l16 = lane & 15;
    const short* aBase = (const short*)A + (size_t)(wave * 16 + l16) * 16384 + ks * 1024 + q * 8;
    int r = tid >> 2, cc = tid & 3;
    const float* bg = w4 + (size_t)(bco * 64 + r) * 16384 + ks * 1024 + cc * 8;

    floatx4 acc[4];
#pragma unroll
    for (int nt = 0; nt < 4; ++nt) acc[nt] = (floatx4){0.f, 0.f, 0.f, 0.f};

    short8 nb[CH];
#pragma unroll
    for (int s = 0; s < CH; ++s) {
        float4 b0 = *(const float4*)(bg + s * 32);
        float4 b1 = *(const float4*)(bg + s * 32 + 4);
        nb[s][0] = (short)f2bf(b0.x); nb[s][1] = (short)f2bf(b0.y);
        nb[s][2] = (short)f2bf(b0.z); nb[s][3] = (short)f2bf(b0.w);
        nb[s][4] = (short)f2bf(b1.x); nb[s][5] = (short)f2bf(b1.y);
        nb[s][6] = (short)f2bf(b1.z); nb[s][7] = (short)f2bf(b1.w);
    }
#pragma unroll
    for (int s = 0; s < CH; ++s) *(short8*)&Bs[s][r][cc * 8] = nb[s];
    __syncthreads();

    for (int chunk = 0; chunk < NCHUNK; ++chunk) {
        bool has_next = (chunk + 1 < NCHUNK);
        if (has_next) {
#pragma unroll
            for (int s = 0; s < CH; ++s) {
                int step = (chunk + 1) * CH + s;
                float4 b0 = *(const float4*)(bg + step * 32);
                float4 b1 = *(const float4*)(bg + step * 32 + 4);
                nb[s][0] = (short)f2bf(b0.x); nb[s][1] = (short)f2bf(b0.y);
                nb[s][2] = (short)f2bf(b0.z); nb[s][3] = (short)f2bf(b0.w);
                nb[s][4] = (short)f2bf(b1.x); nb[s][5] = (short)f2bf(b1.y);
                nb[s][6] = (short)f2bf(b1.z); nb[s][7] = (short)f2bf(b1.w);
            }
        }
#pragma unroll
        for (int s = 0; s < CH; ++s) {
            int step = chunk * CH + s;
            short8 af = *(const short8*)(aBase + step * 32);
#pragma unroll
            for (int nt = 0; nt < 4; ++nt) {
                short8 bf = *(const short8*)&Bs[s][nt * 16 + l16][q * 8];
                acc[nt] = __builtin_amdgcn_mfma_f32_16x16x32_bf16(af, bf, acc[nt], 0, 0, 0);
            }
        }
        if (has_next) {
            __syncthreads();
#pragma unroll
            for (int s = 0; s < CH; ++s) *(short8*)&Bs[s][r][cc * 8] = nb[s];
            __syncthreads();
        }
    }
#pragma unroll
    for (int nt = 0; nt < 4; ++nt) {
#pragma unroll
        for (int rg = 0; rg < 4; ++rg) {
            int mg = wave * 16 + q * 4 + rg;
            int co = bco * 64 + nt * 16 + l16;
            atomicAdd(&h4[(size_t)mg * 1024 + co], acc[nt][rg]);
        }
    }
}

// ----------------------------------------------------------- batch stats ----
__global__ __launch_bounds__(256) void stats_part(const float* __restrict__ X,
                                                  float* __restrict__ acc,
                                                  int CO, int R, int RPB, int CGLOG) {
    int tid = threadIdx.x;
    int cg = blockIdx.x & ((1 << CGLOG) - 1);
    int rb = blockIdx.x >> CGLOG;
    int c = (cg << 6) + (tid & 63);
    int w = tid >> 6;
    float s = 0.f, s2 = 0.f;
    int rend = min(R, (rb + 1) * RPB);
    for (int r = rb * RPB + w; r < rend; r += 4) {
        float v = X[(size_t)r * CO + c];
        s += v; s2 += v * v;
    }
    __shared__ float ls[4][64], ls2[4][64];
    ls[w][tid & 63] = s; ls2[w][tid & 63] = s2;
    __syncthreads();
    if (tid < 64) {
        float ts = ls[0][tid] + ls[1][tid] + ls[2][tid] + ls[3][tid];
        float ts2 = ls2[0][tid] + ls2[1][tid] + ls2[2][tid] + ls2[3][tid];
        int cc = (cg << 6) + tid;
        atomicAdd(&acc[cc], ts);
        atomicAdd(&acc[CO + cc], ts2);
    }
}

// ------------------- BN(inline finalize) + lrelu + pad + bf16 (NHWC) --------
__global__ __launch_bounds__(256) void bnpad_kernel(const float* __restrict__ X,
                                                    const float* __restrict__ stacc,
                                                    const float* __restrict__ g,
                                                    const float* __restrict__ bb,
                                                    unsigned short* __restrict__ out,
                                                    int CO_LOG, int OH, int OHP,
                                                    float invN, int total) {
    int idx = blockIdx.x * 256 + threadIdx.x;
    if (idx >= total) return;
    int CO = 1 << CO_LOG;
    int c = idx & (CO - 1);
    float mean = stacc[c] * invN;
    float var = fmaxf(stacc[CO + c] * invN - mean * mean, 0.f);
    float sc = g[c] * rsqrtf(var + EPS);
    float sh = bb[c] - mean * sc;
    int t = idx >> CO_LOG;
    int x = t % OHP; t /= OHP;
    int y = t % OHP; int b = t / OHP;
    unsigned short v = 0;
    if (y >= 2 && y < OH + 2 && x >= 2 && x < OH + 2) {
        float f = X[(((size_t)(b * OH + (y - 2)) * OH + (x - 2)) << CO_LOG) + c];
        f = f * sc + sh;
        f = f >= 0.f ? f : NEG * f;
        v = f2bf(f);
    }
    out[idx] = v;
}

// -------- BN(inline finalize) + lrelu + bf16, NHWC -> NCHW (conv4 input) ----
__global__ __launch_bounds__(256) void bn_nchw_kernel(const float* __restrict__ X,
                                                      const float* __restrict__ stacc,
                                                      const float* __restrict__ g,
                                                      const float* __restrict__ bb,
                                                      unsigned short* __restrict__ out,
                                                      int total) {
    int idx = blockIdx.x * 256 + threadIdx.x;
    if (idx >= total) return;
    int hw = idx & 63;
    int ci = (idx >> 6) & 255;
    int b = idx >> 14;
    float mean = stacc[ci] * (1.f / 4096.f);
    float var = fmaxf(stacc[256 + ci] * (1.f / 4096.f) - mean * mean, 0.f);
    float sc = g[ci] * rsqrtf(var + EPS);
    float sh = bb[ci] - mean * sc;
    float f = X[((size_t)(b * 64 + hw)) * 256 + ci] * sc + sh;
    f = f >= 0.f ? f : NEG * f;
    out[idx] = f2bf(f);
}

// -------------------------------------- conv5 (inline BN4 finalize) ---------
__global__ __launch_bounds__(256) void conv5_kernel(const float* __restrict__ X,
                                                    const float* __restrict__ stacc,
                                                    const float* __restrict__ g,
                                                    const float* __restrict__ bb,
                                                    const float* __restrict__ w5,
                                                    const float* __restrict__ b5,
                                                    float* __restrict__ out) {
    int b = blockIdx.x, tid = threadIdx.x;
    float s = 0.f;
    for (int c = tid; c < 1024; c += 256) {
        float mean = stacc[c] * (1.f / 64.f);
        float var = fmaxf(stacc[1024 + c] * (1.f / 64.f) - mean * mean, 0.f);
        float sc = g[c] * rsqrtf(var + EPS);
        float sh = bb[c] - mean * sc;
        float f = X[(size_t)b * 1024 + c] * sc + sh;
        f = f >= 0.f ? f : NEG * f;
        s = fmaf(f, w5[c], s);
    }
#pragma unroll
    for (int off = 32; off > 0; off >>= 1) s += __shfl_down(s, off);
    __shared__ float ls[4];
    if ((tid & 63) == 0) ls[tid >> 6] = s;
    __syncthreads();
    if (tid == 0) out[b] = ls[0] + ls[1] + ls[2] + ls[3] + b5[0];
}

// ----------------------------------------------------------------- launch ---
extern "C" void kernel_launch(void* const* d_in, const int* in_sizes, int n_in,
                              void* d_out, int out_size, void* d_ws, size_t ws_size,
                              hipStream_t stream) {
    (void)in_sizes; (void)n_in; (void)out_size; (void)ws_size;
    const float* input_data = (const float*)d_in[0];
    const float* w1 = (const float*)d_in[2];
    const float* g1 = (const float*)d_in[3];
    const float* b1 = (const float*)d_in[4];
    const float* w2 = (const float*)d_in[5];
    const float* g2 = (const float*)d_in[6];
    const float* b2 = (const float*)d_in[7];
    const float* w3 = (const float*)d_in[8];
    const float* g3 = (const float*)d_in[9];
    const float* b3 = (const float*)d_in[10];
    const float* w4 = (const float*)d_in[11];
    const float* g4 = (const float*)d_in[12];
    const float* b4 = (const float*)d_in[13];
    const float* w5 = (const float*)d_in[14];
    const float* b5 = (const float*)d_in[15];

    char* ws = (char*)d_ws;
    float* regA = (float*)ws;               // 16.8 MB: conv1out
    char* wsB = ws + 16777216;              // 10.7 MB: pad1 / pad2
    char* wsC = wsB + 10616832;             // 9.5 MB: rendered / conv2out / a4
    char* wsD = wsC + 9469952;
    float* h4  = (float*)wsD;                               // 262,144 B
    float* st1 = (float*)(wsD + 262144);                    // 512 B  (64*2)
    float* st2 = (float*)(wsD + 262656);                    // 1024 B (128*2)
    float* st3 = (float*)(wsD + 263680);                    // 2048 B (256*2)
    float* st4 = (float*)(wsD + 265728);                    // 8192 B (1024*2)
    float* conv3out = (float*)(wsD + 274432);               // 4,194,304 B (atomic, needs zero)
    unsigned short* wT1 = (unsigned short*)(wsD + 4468736); // 61,440 B
    unsigned short* wT2 = (unsigned short*)(wsD + 4530176); // 409,600 B
    unsigned short* wT3 = (unsigned short*)(wsD + 4939776); // 1,638,400 B

    unsigned short* rendered = (unsigned short*)wsC;
    float* conv1out = regA;
    unsigned short* pad1 = (unsigned short*)wsB;
    float* conv2out = (float*)wsC;
    unsigned short* pad2 = (unsigned short*)wsB;
    unsigned short* a4 = (unsigned short*)wsC;

    // one memset covers h4 + all stat accumulators + conv3out (split-K target)
    hipMemsetAsync(wsD, 0, 4468736, stream);
    // fused render + weight transform
    head_kernel<<<5144, 256, 0, stream>>>(input_data, rendered, w1, w2, w3, wT1, wT2, wT3);

    // conv1: [65536,480]x[480,64] — 256m x 2co = 512 blocks, NT=2, 8 waves/CU
    conv_direct<16, 64, 68, 10, 5, 3, 2, 2, 1><<<512, 256, 0, stream>>>(rendered, wT1, conv1out, st1);
    bnpad_kernel<<<20736, 256, 0, stream>>>(conv1out, st1, g1, b1, pad1, 6, 32, 36, 1.f / 65536.f, 5308416);

    // conv2: [16384,1600]x[1600,128] — 64m x 8co = 512 blocks, NT=1, 8 waves/CU
    conv_direct<64, 128, 36, 8, 4, 10, 8, 1, 1><<<512, 256, 0, stream>>>(pad1, wT2, conv2out, st2);
    bnpad_kernel<<<12800, 256, 0, stream>>>(conv2out, st2, g2, b2, pad2, 7, 16, 20, 1.f / 16384.f, 3276800);

    // conv3: [4096,3200]x[3200,256] — 16m x 8co x 4k = 512 blocks, NT=2, split-K atomics
    conv_direct<128, 256, 20, 6, 3, 20, 8, 2, 4><<<512, 256, 0, stream>>>(pad2, wT3, conv3out, st3);
    stats_part<<<256, 256, 0, stream>>>(conv3out, st3, 256, 4096, 64, 2);
    bn_nchw_kernel<<<4096, 256, 0, stream>>>(conv3out, st3, g3, b3, a4, 1048576);

    // conv4: [64,16384] x [1024,16384]^T -> [64,1024], split-K=16, CH=8
    conv4_mfma<<<256, 256, 0, stream>>>(a4, w4, h4);
    stats_part<<<16, 256, 0, stream>>>(h4, st4, 1024, 64, 64, 4);

    // conv5 (inline BN4)
    conv5_kernel<<<64, 256, 0, stream>>>(h4, st4, g4, b4, w5, b5, (float*)d_out);
}

// Round 4
// 273.437 us; speedup vs baseline: 1.1823x; 1.1823x over previous
//
#include <hip/hip_runtime.h>
#include <hip/hip_bf16.h>

#define NEG 0.01f
#define EPS 1e-5f

typedef __attribute__((ext_vector_type(8))) short short8;
typedef __attribute__((ext_vector_type(4))) float floatx4;

__device__ inline unsigned short f2bf(float f) {
    __hip_bfloat16 h = __float2bfloat16(f);
    union { __hip_bfloat16 h; unsigned short u; } cv; cv.h = h;
    return cv.u;
}

// ---------------------------------------------------------------- render ----
// Writes padded NHWC bf16 [64][68][68][16] INCLUDING zero borders + ch14/15.
__global__ __launch_bounds__(256) void render_kernel(const float* __restrict__ in,
                                                     unsigned short* __restrict__ out) {
    int b = blockIdx.x >> 4;
    int chunk = blockIdx.x & 15;
    __shared__ float r0[46], r1[46], r2[46], r3[46];
    __shared__ float cls_s[46 * 14];
    int tid = threadIdx.x;
    if (tid < 46) {
        const float* p = in + ((size_t)b * 46 + tid) * 18 + 14;
        float x = p[0] * 64.f, y = p[1] * 64.f, w = p[2] * 64.f, h = p[3] * 64.f;
        r0[tid] = x - 0.5f * w; r1[tid] = x + 0.5f * w;
        r2[tid] = y - 0.5f * h; r3[tid] = y + 0.5f * h;
    }
    for (int idx = tid; idx < 46 * 14; idx += 256) {
        int n = idx / 14, c = idx % 14;
        cls_s[idx] = in[((size_t)b * 46 + n) * 18 + c];
    }
    __syncthreads();
    // border zeroing: 528 border px, 33 per block
    if (tid < 33) {
        int j = chunk * 33 + tid;
        if (j < 528) {
            int y, x;
            if (j < 136) { y = j / 68; x = j - y * 68; }
            else if (j < 272) { int t = j - 136; int yy = t / 68; y = 66 + yy; x = t - yy * 68; }
            else { int t = j - 272; y = 2 + (t >> 2); int k = t & 3; x = (k < 2) ? k : 64 + k; }
            size_t zb = (((size_t)b * 68 + y) * 68 + x) * 16;
            short8 z;
#pragma unroll
            for (int i = 0; i < 8; ++i) z[i] = 0;
            *(short8*)(out + zb) = z;
            *(short8*)(out + zb + 8) = z;
        }
    }
    int pix = chunk * 256 + tid;
    float cx = (float)(pix & 63);
    float cy = (float)(pix >> 6);
    float acc[14];
#pragma unroll
    for (int c = 0; c < 14; ++c) acc[c] = 0.f;
    for (int n = 0; n < 46; ++n) {
        float x0 = r0[n], x1 = r1[n], y0 = r2[n], y1 = r3[n];
        float by = fminf(fmaxf(cy - y0, 0.f), 1.f) * fminf(fmaxf(y1 - cy, 0.f), 1.f);
        float bx = fminf(fmaxf(cx - x0, 0.f), 1.f) * fminf(fmaxf(x1 - cx, 0.f), 1.f);
        float kx0 = fmaxf(1.f - fabsf(cx - x0), 0.f);
        float kx1 = fmaxf(1.f - fabsf(cx - x1), 0.f);
        float ky0 = fmaxf(1.f - fabsf(cy - y0), 0.f);
        float ky1 = fmaxf(1.f - fabsf(cy - y1), 0.f);
        float r = fmaxf(fmaxf(kx0 * by, kx1 * by), fmaxf(ky0 * bx, ky1 * bx));
        if (r > 0.f) {
#pragma unroll
            for (int c = 0; c < 14; ++c) acc[c] = fmaf(cls_s[n * 14 + c], r, acc[c]);
        }
    }
    size_t obase = (((size_t)b * 68 + ((pix >> 6) + 2)) * 68 + ((pix & 63) + 2)) * 16;
    short8 v0, v1;
#pragma unroll
    for (int i = 0; i < 8; ++i) v0[i] = (short)f2bf(acc[i]);
#pragma unroll
    for (int i = 0; i < 6; ++i) v1[i] = (short)f2bf(acc[8 + i]);
    v1[6] = 0; v1[7] = 0;
    *(short8*)(out + obase) = v0;
    *(short8*)(out + obase + 8) = v1;
}

// ------------------------------------------- merged weight transform --------
__global__ __launch_bounds__(256) void wtrans_all(const float* __restrict__ w1,
                                                  const float* __restrict__ w2,
                                                  const float* __restrict__ w3,
                                                  unsigned short* __restrict__ wT1,
                                                  unsigned short* __restrict__ wT2,
                                                  unsigned short* __restrict__ wT3) {
    int idx = blockIdx.x * 256 + threadIdx.x;
    const float* w; unsigned short* wT; int CIN, CPLOG, SUB, COLOG;
    if (idx < 30720) { w = w1; wT = wT1; CIN = 14; CPLOG = 4; SUB = 3; COLOG = 6; }
    else if (idx < 235520) { idx -= 30720; w = w2; wT = wT2; CIN = 64; CPLOG = 6; SUB = 10; COLOG = 7; }
    else if (idx < 1054720) { idx -= 235520; w = w3; wT = wT3; CIN = 128; CPLOG = 7; SUB = 20; COLOG = 8; }
    else return;
    int kk = idx & 31;
    int co = (idx >> 5) & ((1 << COLOG) - 1);
    int s = idx >> (5 + COLOG);
    int kh = s / SUB, sub = s - kh * SUB;
    int kidx = sub * 32 + kk;
    int kw = kidx >> CPLOG;
    int ci = kidx & ((1 << CPLOG) - 1);
    float v = (kw < 5 && ci < CIN) ? w[((size_t)(co * CIN + ci) * 5 + kh) * 5 + kw] : 0.f;
    wT[idx] = f2bf(v);
}

// ------------------------------------------- implicit-GEMM MFMA conv --------
// NW-wave blocks. Each wave: 64 px (4 f-frags) x NT*16 co -> 4*NT MFMA/step.
// A loaded directly from padded NHWC global (per-lane, coalesced). B staged
// cooperatively into double-buffered LDS, ONE barrier per CH-step chunk.
// XCD-aware bijective swizzle: HW dispatches consecutive blockIdx round-robin
// across the 8 XCDs; remap so each XCD owns a CONTIGUOUS lb-range, putting
// the NCO co-split blocks that share an A-tile on the SAME private L2
// (R1 PMC: conv3 fetched 40.8 MB vs 6.5 MB input = 6x overfetch without this).
// Fused BN stats: block-local LDS reduce, then 1 atomic per channel per block.
template <int CP, int COUT, int HP, int LOG_OHW, int LOG_OW, int SUB,
          int NCO, int NT, int CH, int NW>
__global__ __launch_bounds__(NW * 64) void conv_mfma(
        const unsigned short* __restrict__ inP,
        const unsigned short* __restrict__ wT,
        float* __restrict__ outX,
        float* __restrict__ stacc) {
    constexpr int NSTEP = 5 * SUB;
    constexpr int NCHUNK = NSTEP / CH;
    constexpr int COT = NT * 16;
    constexpr int NSTG = (CH * COT * 4) / (NW * 64);
    static_assert(NSTEP % CH == 0, "CH must divide NSTEP");
    static_assert((CH * COT * 4) % (NW * 64) == 0, "staging must tile evenly");
    __shared__ short Bs[2][CH][COT][32];
    __shared__ float sred[NW][2][COT];
    int tid = threadIdx.x;
    int wave = tid >> 6, lane = tid & 63, q = lane >> 4, l16 = lane & 15;
    // XCD swizzle (grid % 8 == 0 for all launches)
    int cpx = gridDim.x >> 3;
    int lb = (blockIdx.x & 7) * cpx + (blockIdx.x >> 3);
    int bm = lb / NCO, bco = lb % NCO;

    const short* aB[4];
#pragma unroll
    for (int f = 0; f < 4; ++f) {
        int m = bm * (NW * 64) + wave * 64 + f * 16 + l16;
        int b = m >> LOG_OHW;
        int ohw = m & ((1 << LOG_OHW) - 1);
        int oh = ohw >> LOG_OW, ow = ohw & ((1 << LOG_OW) - 1);
        aB[f] = (const short*)inP + ((size_t)((b * HP + 2 * oh) * HP + 2 * ow)) * CP + q * 8;
    }
    const short* bgbase = (const short*)wT + (size_t)bco * COT * 32;

    floatx4 acc[4][NT];
#pragma unroll
    for (int f = 0; f < 4; ++f)
#pragma unroll
        for (int nt = 0; nt < NT; ++nt) acc[f][nt] = (floatx4){0.f, 0.f, 0.f, 0.f};

    short8 nb[NSTG];
    // stage chunk 0
#pragma unroll
    for (int i = 0; i < NSTG; ++i) {
        int v = tid + i * NW * 64;
        int s = v / (COT * 4);
        int rem = v - s * (COT * 4);
        nb[i] = *(const short8*)(bgbase + ((size_t)s * COUT) * 32 + rem * 8);
    }
#pragma unroll
    for (int i = 0; i < NSTG; ++i) {
        int v = tid + i * NW * 64;
        int s = v / (COT * 4);
        int rem = v - s * (COT * 4);
        *(short8*)((short*)&Bs[0][s][0][0] + rem * 8) = nb[i];
    }
    __syncthreads();

    for (int chunk = 0; chunk < NCHUNK; ++chunk) {
        int cur = chunk & 1;
        if (chunk + 1 < NCHUNK) {
            int step0 = (chunk + 1) * CH;
#pragma unroll
            for (int i = 0; i < NSTG; ++i) {
                int v = tid + i * NW * 64;
                int s = v / (COT * 4);
                int rem = v - s * (COT * 4);
                nb[i] = *(const short8*)(bgbase + ((size_t)(step0 + s) * COUT) * 32 + rem * 8);
            }
        }
#pragma unroll
        for (int s = 0; s < CH; ++s) {
            int step = chunk * CH + s;
            int kh = step / SUB, sub = step - kh * SUB;
            short8 af[4];
#pragma unroll
            for (int f = 0; f < 4; ++f)
                af[f] = *(const short8*)(aB[f] + (size_t)(kh * HP) * CP + sub * 32);
#pragma unroll
            for (int nt = 0; nt < NT; ++nt) {
                short8 bf = *(const short8*)&Bs[cur][s][nt * 16 + l16][q * 8];
#pragma unroll
                for (int f = 0; f < 4; ++f)
                    acc[f][nt] = __builtin_amdgcn_mfma_f32_16x16x32_bf16(af[f], bf, acc[f][nt], 0, 0, 0);
            }
        }
        if (chunk + 1 < NCHUNK) {
#pragma unroll
            for (int i = 0; i < NSTG; ++i) {
                int v = tid + i * NW * 64;
                int s = v / (COT * 4);
                int rem = v - s * (COT * 4);
                *(short8*)((short*)&Bs[cur ^ 1][s][0][0] + rem * 8) = nb[i];
            }
            __syncthreads();
        }
    }
    // output
#pragma unroll
    for (int f = 0; f < 4; ++f)
#pragma unroll
        for (int nt = 0; nt < NT; ++nt)
#pragma unroll
            for (int rg = 0; rg < 4; ++rg) {
                int mg = bm * (NW * 64) + wave * 64 + f * 16 + q * 4 + rg;
                int co = bco * COT + nt * 16 + l16;
                outX[(size_t)mg * COUT + co] = acc[f][nt][rg];
            }
    // fused BN stats: wave shfl-reduce -> LDS -> one atomic per co per block
#pragma unroll
    for (int nt = 0; nt < NT; ++nt) {
        float s = 0.f, s2 = 0.f;
#pragma unroll
        for (int f = 0; f < 4; ++f)
#pragma unroll
            for (int rg = 0; rg < 4; ++rg) {
                float v = acc[f][nt][rg];
                s += v; s2 = fmaf(v, v, s2);
            }
        s += __shfl_xor(s, 16); s += __shfl_xor(s, 32);
        s2 += __shfl_xor(s2, 16); s2 += __shfl_xor(s2, 32);
        if (q == 0) {
            sred[wave][0][nt * 16 + l16] = s;
            sred[wave][1][nt * 16 + l16] = s2;
        }
    }
    __syncthreads();
    if (tid < COT) {
        float ts = 0.f, ts2 = 0.f;
#pragma unroll
        for (int w = 0; w < NW; ++w) { ts += sred[w][0][tid]; ts2 += sred[w][1][tid]; }
        atomicAdd(&stacc[bco * COT + tid], ts);
        atomicAdd(&stacc[COUT + bco * COT + tid], ts2);
    }
}

// --------------------------------------------------- conv4 split-K GEMM -----
__global__ __launch_bounds__(256) void conv4_mfma(const unsigned short* __restrict__ A,
                                                  const float* __restrict__ w4,
                                                  float* __restrict__ h4) {
    constexpr int CH = 4, NCHUNK = 8;
    __shared__ short Bs[CH][64][40];
    int tid = threadIdx.x;
    int bco = blockIdx.x & 15;
    int ks = blockIdx.x >> 4;
    int wave = tid >> 6, lane = tid & 63, q = lane >> 4, l16 = lane & 15;
    const short* aBase = (const short*)A + (size_t)(wave * 16 + l16) * 16384 + ks * 1024 + q * 8;
    int r = tid >> 2, cc = tid & 3;
    const float* bg = w4 + (size_t)(bco * 64 + r) * 16384 + ks * 1024 + cc * 8;

    floatx4 acc[4];
#pragma unroll
    for (int nt = 0; nt < 4; ++nt) acc[nt] = (floatx4){0.f, 0.f, 0.f, 0.f};

    short8 nb[CH];
#pragma unroll
    for (int s = 0; s < CH; ++s) {
        float4 b0 = *(const float4*)(bg + s * 32);
        float4 b1 = *(const float4*)(bg + s * 32 + 4);
        nb[s][0] = (short)f2bf(b0.x); nb[s][1] = (short)f2bf(b0.y);
        nb[s][2] = (short)f2bf(b0.z); nb[s][3] = (short)f2bf(b0.w);
        nb[s][4] = (short)f2bf(b1.x); nb[s][5] = (short)f2bf(b1.y);
        nb[s][6] = (short)f2bf(b1.z); nb[s][7] = (short)f2bf(b1.w);
    }
#pragma unroll
    for (int s = 0; s < CH; ++s) *(short8*)&Bs[s][r][cc * 8] = nb[s];
    __syncthreads();

    for (int chunk = 0; chunk < NCHUNK; ++chunk) {
        bool has_next = (chunk + 1 < NCHUNK);
        if (has_next) {
#pragma unroll
            for (int s = 0; s < CH; ++s) {
                int step = (chunk + 1) * CH + s;
                float4 b0 = *(const float4*)(bg + step * 32);
                float4 b1 = *(const float4*)(bg + step * 32 + 4);
                nb[s][0] = (short)f2bf(b0.x); nb[s][1] = (short)f2bf(b0.y);
                nb[s][2] = (short)f2bf(b0.z); nb[s][3] = (short)f2bf(b0.w);
                nb[s][4] = (short)f2bf(b1.x); nb[s][5] = (short)f2bf(b1.y);
                nb[s][6] = (short)f2bf(b1.z); nb[s][7] = (short)f2bf(b1.w);
            }
        }
#pragma unroll
        for (int s = 0; s < CH; ++s) {
            int step = chunk * CH + s;
            short8 af = *(const short8*)(aBase + step * 32);
#pragma unroll
            for (int nt = 0; nt < 4; ++nt) {
                short8 bf = *(const short8*)&Bs[s][nt * 16 + l16][q * 8];
                acc[nt] = __builtin_amdgcn_mfma_f32_16x16x32_bf16(af, bf, acc[nt], 0, 0, 0);
            }
        }
        if (has_next) {
            __syncthreads();
#pragma unroll
            for (int s = 0; s < CH; ++s) *(short8*)&Bs[s][r][cc * 8] = nb[s];
            __syncthreads();
        }
    }
#pragma unroll
    for (int nt = 0; nt < 4; ++nt) {
#pragma unroll
        for (int rg = 0; rg < 4; ++rg) {
            int mg = wave * 16 + q * 4 + rg;
            int co = bco * 64 + nt * 16 + l16;
            atomicAdd(&h4[(size_t)mg * 1024 + co], acc[nt][rg]);
        }
    }
}

// ----------------------------------------------------------- batch stats ----
__global__ __launch_bounds__(256) void stats_part(const float* __restrict__ X,
                                                  float* __restrict__ acc,
                                                  int CO, int R, int RPB, int CGLOG) {
    int tid = threadIdx.x;
    int cg = blockIdx.x & ((1 << CGLOG) - 1);
    int rb = blockIdx.x >> CGLOG;
    int c = (cg << 6) + (tid & 63);
    int w = tid >> 6;
    float s = 0.f, s2 = 0.f;
    int rend = min(R, (rb + 1) * RPB);
    for (int r = rb * RPB + w; r < rend; r += 4) {
        float v = X[(size_t)r * CO + c];
        s += v; s2 += v * v;
    }
    __shared__ float ls[4][64], ls2[4][64];
    ls[w][tid & 63] = s; ls2[w][tid & 63] = s2;
    __syncthreads();
    if (tid < 64) {
        float ts = ls[0][tid] + ls[1][tid] + ls[2][tid] + ls[3][tid];
        float ts2 = ls2[0][tid] + ls2[1][tid] + ls2[2][tid] + ls2[3][tid];
        int cc = (cg << 6) + tid;
        atomicAdd(&acc[cc], ts);
        atomicAdd(&acc[CO + cc], ts2);
    }
}

// ------------------- BN(inline finalize) + lrelu + pad + bf16 (NHWC) --------
__global__ __launch_bounds__(256) void bnpad_kernel(const float* __restrict__ X,
                                                    const float* __restrict__ stacc,
                                                    const float* __restrict__ g,
                                                    const float* __restrict__ bb,
                                                    unsigned short* __restrict__ out,
                                                    int CO_LOG, int OH, int OHP,
                                                    float invN, int total) {
    int idx = blockIdx.x * 256 + threadIdx.x;
    if (idx >= total) return;
    int CO = 1 << CO_LOG;
    int c = idx & (CO - 1);
    float mean = stacc[c] * invN;
    float var = fmaxf(stacc[CO + c] * invN - mean * mean, 0.f);
    float sc = g[c] * rsqrtf(var + EPS);
    float sh = bb[c] - mean * sc;
    int t = idx >> CO_LOG;
    int x = t % OHP; t /= OHP;
    int y = t % OHP; int b = t / OHP;
    unsigned short v = 0;
    if (y >= 2 && y < OH + 2 && x >= 2 && x < OH + 2) {
        float f = X[(((size_t)(b * OH + (y - 2)) * OH + (x - 2)) << CO_LOG) + c];
        f = f * sc + sh;
        f = f >= 0.f ? f : NEG * f;
        v = f2bf(f);
    }
    out[idx] = v;
}

// -------- BN(inline finalize) + lrelu + bf16, NHWC -> NCHW (conv4 input) ----
__global__ __launch_bounds__(256) void bn_nchw_kernel(const float* __restrict__ X,
                                                      const float* __restrict__ stacc,
                                                      const float* __restrict__ g,
                                                      const float* __restrict__ bb,
                                                      unsigned short* __restrict__ out,
                                                      int total) {
    int idx = blockIdx.x * 256 + threadIdx.x;
    if (idx >= total) return;
    int hw = idx & 63;
    int ci = (idx >> 6) & 255;
    int b = idx >> 14;
    float mean = stacc[ci] * (1.f / 4096.f);
    float var = fmaxf(stacc[256 + ci] * (1.f / 4096.f) - mean * mean, 0.f);
    float sc = g[ci] * rsqrtf(var + EPS);
    float sh = bb[ci] - mean * sc;
    float f = X[((size_t)(b * 64 + hw)) * 256 + ci] * sc + sh;
    f = f >= 0.f ? f : NEG * f;
    out[idx] = f2bf(f);
}

// -------------------------------------- conv5 (inline BN4 finalize) ---------
__global__ __launch_bounds__(256) void conv5_kernel(const float* __restrict__ X,
                                                    const float* __restrict__ stacc,
                                                    const float* __restrict__ g,
                                                    const float* __restrict__ bb,
                                                    const float* __restrict__ w5,
                                                    const float* __restrict__ b5,
                                                    float* __restrict__ out) {
    int b = blockIdx.x, tid = threadIdx.x;
    float s = 0.f;
    for (int c = tid; c < 1024; c += 256) {
        float mean = stacc[c] * (1.f / 64.f);
        float var = fmaxf(stacc[1024 + c] * (1.f / 64.f) - mean * mean, 0.f);
        float sc = g[c] * rsqrtf(var + EPS);
        float sh = bb[c] - mean * sc;
        float f = X[(size_t)b * 1024 + c] * sc + sh;
        f = f >= 0.f ? f : NEG * f;
        s = fmaf(f, w5[c], s);
    }
#pragma unroll
    for (int off = 32; off > 0; off >>= 1) s += __shfl_down(s, off);
    __shared__ float ls[4];
    if ((tid & 63) == 0) ls[tid >> 6] = s;
    __syncthreads();
    if (tid == 0) out[b] = ls[0] + ls[1] + ls[2] + ls[3] + b5[0];
}

// ----------------------------------------------------------------- launch ---
extern "C" void kernel_launch(void* const* d_in, const int* in_sizes, int n_in,
                              void* d_out, int out_size, void* d_ws, size_t ws_size,
                              hipStream_t stream) {
    (void)in_sizes; (void)n_in; (void)out_size; (void)ws_size;
    const float* input_data = (const float*)d_in[0];
    const float* w1 = (const float*)d_in[2];
    const float* g1 = (const float*)d_in[3];
    const float* b1 = (const float*)d_in[4];
    const float* w2 = (const float*)d_in[5];
    const float* g2 = (const float*)d_in[6];
    const float* b2 = (const float*)d_in[7];
    const float* w3 = (const float*)d_in[8];
    const float* g3 = (const float*)d_in[9];
    const float* b3 = (const float*)d_in[10];
    const float* w4 = (const float*)d_in[11];
    const float* g4 = (const float*)d_in[12];
    const float* b4 = (const float*)d_in[13];
    const float* w5 = (const float*)d_in[14];
    const float* b5 = (const float*)d_in[15];

    char* ws = (char*)d_ws;
    float* regA = (float*)ws;               // 16.8 MB: conv1out / conv3out
    char* wsB = ws + 16777216;              // 10.7 MB: pad1 / pad2
    char* wsC = wsB + 10616832;             // 9.5 MB: rendered / conv2out / a4
    char* wsD = wsC + 9469952;
    float* h4  = (float*)wsD;                               // 262,144 B
    float* st1 = (float*)(wsD + 262144);                    // 512 B  (64*2)
    float* st2 = (float*)(wsD + 262656);                    // 1024 B (128*2)
    float* st3 = (float*)(wsD + 263680);                    // 2048 B (256*2)
    float* st4 = (float*)(wsD + 265728);                    // 8192 B (1024*2)
    unsigned short* wT1 = (unsigned short*)(wsD + 274432);  // 61,440 B
    unsigned short* wT2 = (unsigned short*)(wsD + 335872);  // 409,600 B
    unsigned short* wT3 = (unsigned short*)(wsD + 745472);  // 1,638,400 B

    unsigned short* rendered = (unsigned short*)wsC;
    float* conv1out = regA;
    unsigned short* pad1 = (unsigned short*)wsB;
    float* conv2out = (float*)wsC;
    unsigned short* pad2 = (unsigned short*)wsB;
    float* conv3out = regA;
    unsigned short* a4 = (unsigned short*)wsC;

    // one memset covers h4 + all stat accumulators
    hipMemsetAsync(wsD, 0, 273920, stream);
    wtrans_all<<<4120, 256, 0, stream>>>(w1, w2, w3, wT1, wT2, wT3);
    render_kernel<<<1024, 256, 0, stream>>>(input_data, rendered);

    // conv1: [65536,480]x[480,64] — 256 blocks x 4 waves, NT=4, CH=5 (3 chunks)
    conv_mfma<16, 64, 68, 10, 5, 3, 1, 4, 5, 4><<<256, 256, 0, stream>>>(rendered, wT1, conv1out, st1);
    bnpad_kernel<<<20736, 256, 0, stream>>>(conv1out, st1, g1, b1, pad1, 6, 32, 36, 1.f / 65536.f, 5308416);

    // conv2: [16384,1600]x[1600,128] — 64m x 4co = 256 blocks, NT=2, CH=10 (5 chunks)
    conv_mfma<64, 128, 36, 8, 4, 10, 4, 2, 10, 4><<<256, 256, 0, stream>>>(pad1, wT2, conv2out, st2);
    bnpad_kernel<<<12800, 256, 0, stream>>>(conv2out, st2, g2, b2, pad2, 7, 16, 20, 1.f / 16384.f, 3276800);

    // conv3: [4096,3200]x[3200,256] — 32m x 8co = 256 blocks of 2 waves, NT=2, CH=10
    conv_mfma<128, 256, 20, 6, 3, 20, 8, 2, 10, 2><<<256, 128, 0, stream>>>(pad2, wT3, conv3out, st3);
    bn_nchw_kernel<<<4096, 256, 0, stream>>>(conv3out, st3, g3, b3, a4, 1048576);

    // conv4: [64,16384] x [1024,16384]^T -> [64,1024], split-K=16
    conv4_mfma<<<256, 256, 0, stream>>>(a4, w4, h4);
    stats_part<<<16, 256, 0, stream>>>(h4, st4, 1024, 64, 64, 4);

    // conv5 (inline BN4)
    conv5_kernel<<<64, 256, 0, stream>>>(h4, st4, g4, b4, w5, b5, (float*)d_out);
}